// Round 9
// baseline (814.442 us; speedup 1.0000x reference)
//
#include <hip/hip_runtime.h>
#include <hip/hip_fp16.h>
#include <math.h>

// Problem constants (match reference)
#define N_PTS   192000
#define NPATCH  4000      // N/48
#define PK      48        // patch size
#define NH      4         // heads
#define HD      16        // head dim

// Inline erf (Abramowitz & Stegun 7.1.26, |eps| <= 1.5e-7), no libm call.
__device__ __forceinline__ float erf_inl(float x) {
    float ax = fabsf(x);
    float t = 1.0f / fmaf(0.3275911f, ax, 1.0f);
    float poly = fmaf(1.061405429f, t, -1.453152027f);
    poly = fmaf(poly, t, 1.421413741f);
    poly = fmaf(poly, t, -0.284496736f);
    poly = fmaf(poly, t, 0.254829592f);
    poly *= t;
    float e = __expf(-ax * ax);          // native v_exp_f32
    float r = 1.0f - poly * e;
    return copysignf(r, x);
}

__device__ __forceinline__ float gelu_exact(float x) {
    return 0.5f * x * (1.0f + erf_inl(x * 0.70710678118654752f));
}

// ---------------------------------------------------------------------------
// K1: per-point (lane=point): softmax(seg,20)+coord -> feat -> LN1 -> qkv.
// THIS ROUND: qkv loop restructured to the R8-validated k_ffn shape —
// LN1 output h[64] lives in fp16 LDS (own column, no barrier), qkv computed
// in 12 chunks of 16 outputs with wave-uniform weight reads.
// ---------------------------------------------------------------------------
__global__ __launch_bounds__(256) void k_in_qkv(
    const float* __restrict__ seg, const float* __restrict__ coord,
    const float* __restrict__ W_in, const float* __restrict__ b_in,
    const float* __restrict__ g1, const float* __restrict__ be1,
    const float* __restrict__ W_qkv, const float* __restrict__ b_qkv,
    float* __restrict__ feat_out, float* __restrict__ qkv_out)
{
    __shared__ __half shh[64][256];   // 32 KB; h[c] of thread t at [c][t]

    int tid = threadIdx.x;
    int i = blockIdx.x * 256 + tid;
    if (i >= N_PTS) return;

    float iv[23];
    {
        const float* s = seg + (size_t)i * 20;
        float mx = -1e30f;
        #pragma unroll
        for (int j = 0; j < 20; ++j) { iv[j] = s[j]; mx = fmaxf(mx, iv[j]); }
        float sum = 0.f;
        #pragma unroll
        for (int j = 0; j < 20; ++j) { iv[j] = __expf(iv[j] - mx); sum += iv[j]; }
        float r = 1.f / sum;
        #pragma unroll
        for (int j = 0; j < 20; ++j) iv[j] *= r;
        iv[20] = coord[(size_t)i*3 + 0];
        iv[21] = coord[(size_t)i*3 + 1];
        iv[22] = coord[(size_t)i*3 + 2];
    }

    // feat = iv @ W_in + b_in   (23x64), W_in row-major [23][64]
    float f[64];
    #pragma unroll
    for (int c = 0; c < 64; ++c) {
        float a = b_in[c];
        #pragma unroll
        for (int j = 0; j < 23; ++j) a = fmaf(iv[j], W_in[j*64 + c], a);
        f[c] = a;
    }
    // store feat (residual use in k_ffn)
    {
        float4* fd = (float4*)(feat_out + (size_t)i * 64);
        #pragma unroll
        for (int c4 = 0; c4 < 16; ++c4)
            fd[c4] = make_float4(f[4*c4], f[4*c4+1], f[4*c4+2], f[4*c4+3]);
    }
    // LN1 -> h stored to own fp16 LDS column (same-thread RAW only)
    {
        float m = 0.f;
        #pragma unroll
        for (int c = 0; c < 64; ++c) m += f[c];
        m *= (1.f/64.f);
        float v = 0.f;
        #pragma unroll
        for (int c = 0; c < 64; ++c) { float d = f[c]-m; v = fmaf(d, d, v); }
        v *= (1.f/64.f);
        float rs = 1.f / sqrtf(v + 1e-5f);
        #pragma unroll
        for (int c = 0; c < 64; ++c)
            shh[c][tid] = __float2half((f[c]-m)*rs*g1[c] + be1[c]);
    }
    // qkv = h @ W_qkv + b_qkv in 12 chunks of 16 outputs (k_ffn shape)
    for (int ch = 0; ch < 12; ++ch) {
        float a[16];
        #pragma unroll
        for (int t = 0; t < 16; ++t) a[t] = b_qkv[ch*16 + t];
        #pragma unroll
        for (int c = 0; c < 64; ++c) {
            float hv = __half2float(shh[c][tid]);
            const float* w = W_qkv + c*192 + ch*16;
            #pragma unroll
            for (int t = 0; t < 16; ++t) a[t] = fmaf(hv, w[t], a[t]);
        }
        float4* qd = (float4*)(qkv_out + (size_t)i * 192 + ch*16);
        #pragma unroll
        for (int q = 0; q < 4; ++q)
            qd[q] = make_float4(a[4*q], a[4*q+1], a[4*q+2], a[4*q+3]);
    }
}

// ---------------------------------------------------------------------------
// K2: windowed attention. THIS ROUND: rpe_s transposed to [h][69] so a wave
// (uniform h, per-lane idx) reads 23 consecutive words -> conflict-free
// (was banks 4*idx+h -> 3-way conflicts, 5.8M SQ_LDS_BANK_CONFLICT).
// ---------------------------------------------------------------------------
__global__ __launch_bounds__(256) void k_attn(
    const float* __restrict__ qkv, const int* __restrict__ order,
    const int* __restrict__ grid_coord, const float* __restrict__ rpe,
    float* __restrict__ outb)
{
    __shared__ float q_s[NH][PK][17];
    __shared__ float k_s[NH][PK][HD];
    __shared__ float v_s[NH][PK][HD];
    __shared__ float rpe_s[276];        // [h][69] transposed layout
    __shared__ int   ord_s[PK];
    __shared__ int   gc_s[PK][3];

    int p = blockIdx.x;
    int tid = threadIdx.x;

    if (tid < PK) ord_s[tid] = order[p*PK + tid];
    for (int t = tid; t < 276; t += 256) {
        int hh2 = t / 69;               // dest head
        int idx = t - hh2 * 69;         // dest rpe index
        rpe_s[t] = rpe[idx*4 + hh2];    // src layout [69][4]
    }
    __syncthreads();

    if (tid < PK) {
        int row = ord_s[tid];
        gc_s[tid][0] = grid_coord[(size_t)row*3 + 0];
        gc_s[tid][1] = grid_coord[(size_t)row*3 + 1];
        gc_s[tid][2] = grid_coord[(size_t)row*3 + 2];
    }
    {
        int lane = tid & 63;
        int hh = lane >> 4, dd = lane & 15;
        for (int rr = tid >> 6; rr < PK; rr += 4) {
            const float* src = qkv + (size_t)ord_s[rr] * 192;
            float qv = src[lane];
            float kv = src[64 + lane];
            float vv = src[128 + lane];
            q_s[hh][rr][dd] = qv;
            k_s[hh][rr][dd] = kv;
            v_s[hh][rr][dd] = vv;
        }
    }
    __syncthreads();

    int h = tid >> 6;
    int r = tid & 63;
    if (r >= PK) return;

    float qr[HD];
    #pragma unroll
    for (int d = 0; d < HD; ++d) qr[d] = q_s[h][r][d];
    int gx = gc_s[r][0], gy = gc_s[r][1], gz = gc_s[r][2];
    int h69 = h * 69;

    float s[PK];
    #pragma unroll 4
    for (int m = 0; m < PK; ++m) {
        float a = 0.f;
        #pragma unroll
        for (int d = 0; d < HD; ++d) a = fmaf(qr[d], k_s[h][m][d], a);
        a *= 0.25f;
        int i0 = min(max(gx - gc_s[m][0], -11), 11) + 11;
        int i1 = min(max(gy - gc_s[m][1], -11), 11) + 34;
        int i2 = min(max(gz - gc_s[m][2], -11), 11) + 57;
        a += rpe_s[h69 + i0] + rpe_s[h69 + i1] + rpe_s[h69 + i2];
        s[m] = a;
    }

    float mx = -1e30f;
    #pragma unroll
    for (int m = 0; m < PK; ++m) mx = fmaxf(mx, s[m]);
    float sum = 0.f;
    #pragma unroll
    for (int m = 0; m < PK; ++m) { s[m] = __expf(s[m] - mx); sum += s[m]; }
    float rinv = 1.f / sum;

    float acc[HD];
    #pragma unroll
    for (int d = 0; d < HD; ++d) acc[d] = 0.f;
    #pragma unroll 4
    for (int m = 0; m < PK; ++m) {
        float pv = s[m] * rinv;
        #pragma unroll
        for (int d = 0; d < HD; ++d) acc[d] = fmaf(pv, v_s[h][m][d], acc[d]);
    }
    {
        float* dst = outb + (size_t)ord_s[r]*64 + h*HD;
        float4* d4 = (float4*)dst;
        #pragma unroll
        for (int d4i = 0; d4i < 4; ++d4i)
            d4[d4i] = make_float4(acc[4*d4i], acc[4*d4i+1], acc[4*d4i+2], acc[4*d4i+3]);
    }
}

// ---------------------------------------------------------------------------
// K3: R8-validated version, UNCHANGED (305 µs, VALUBusy 64%, no scratch).
// ---------------------------------------------------------------------------
__global__ __launch_bounds__(256) void k_ffn(
    const float* __restrict__ outb, const float* __restrict__ featb,
    const float* __restrict__ W_attn, const float* __restrict__ b_attn,
    const float* __restrict__ g2, const float* __restrict__ be2,
    const float* __restrict__ W_f1, const float* __restrict__ b_f1,
    const float* __restrict__ W_f2, const float* __restrict__ b_f2,
    const float* __restrict__ W_h1, const float* __restrict__ b_h1,
    const float* __restrict__ W_h2, const float* __restrict__ b_h2,
    float* __restrict__ out)
{
    __shared__ __half shh[64][256];   // 32 KB; hh[c] of thread t at [c][t]

    int tid = threadIdx.x;
    int i = blockIdx.x * 256 + tid;
    if (i >= N_PTS) return;

    float o[64];
    {
        const float4* os = (const float4*)(outb + (size_t)i * 64);
        #pragma unroll
        for (int c4 = 0; c4 < 16; ++c4) {
            float4 t = os[c4];
            o[4*c4]=t.x; o[4*c4+1]=t.y; o[4*c4+2]=t.z; o[4*c4+3]=t.w;
        }
    }
    // attn_out = o @ W_attn + b_attn  (64x64)
    float f[64];
    #pragma unroll
    for (int c = 0; c < 64; ++c) {
        float a = b_attn[c];
        #pragma unroll
        for (int k = 0; k < 64; ++k) a = fmaf(o[k], W_attn[k*64 + c], a);
        f[c] = a;
    }
    // + residual feat
    {
        const float4* fs = (const float4*)(featb + (size_t)i * 64);
        #pragma unroll
        for (int c4 = 0; c4 < 16; ++c4) {
            float4 t = fs[c4];
            f[4*c4]+=t.x; f[4*c4+1]+=t.y; f[4*c4+2]+=t.z; f[4*c4+3]+=t.w;
        }
    }
    // LN2 -> hh stored to own LDS column (same-thread RAW only, no barrier)
    {
        float m = 0.f;
        #pragma unroll
        for (int c = 0; c < 64; ++c) m += f[c];
        m *= (1.f/64.f);
        float v = 0.f;
        #pragma unroll
        for (int c = 0; c < 64; ++c) { float d = f[c]-m; v = fmaf(d, d, v); }
        v *= (1.f/64.f);
        float rs = 1.f / sqrtf(v + 1e-5f);
        #pragma unroll
        for (int c = 0; c < 64; ++c)
            shh[c][tid] = __float2half((f[c]-m)*rs*g2[c] + be2[c]);
    }
    // FFN residual: f += gelu(hh@W_f1+b_f1)@W_f2 + b_f2 ; chunked 16 cols
    #pragma unroll
    for (int c = 0; c < 64; ++c) f[c] += b_f2[c];
    for (int t0 = 0; t0 < 16; ++t0) {
        float a[16];
        #pragma unroll
        for (int tt = 0; tt < 16; ++tt) a[tt] = b_f1[t0*16 + tt];
        #pragma unroll
        for (int c = 0; c < 64; ++c) {
            float hv = __half2float(shh[c][tid]);
            const float* w = W_f1 + c*256 + t0*16;
            #pragma unroll
            for (int tt = 0; tt < 16; ++tt) a[tt] = fmaf(hv, w[tt], a[tt]);
        }
        #pragma unroll
        for (int tt = 0; tt < 16; ++tt) a[tt] = gelu_exact(a[tt]);
        #pragma unroll
        for (int tt = 0; tt < 16; ++tt) {
            float av = a[tt];
            const float* w2 = W_f2 + (t0*16 + tt)*64;
            #pragma unroll
            for (int c = 0; c < 64; ++c) f[c] = fmaf(av, w2[c], f[c]);
        }
    }
    // head: gelu(f@W_h1+b_h1) @ W_h2 + b_h2
    float g[32];
    #pragma unroll
    for (int t = 0; t < 32; ++t) {
        float a = b_h1[t];
        #pragma unroll
        for (int c = 0; c < 64; ++c) a = fmaf(f[c], W_h1[c*32 + t], a);
        g[t] = gelu_exact(a);
    }
    #pragma unroll
    for (int r = 0; r < 3; ++r) {
        float a = b_h2[r];
        #pragma unroll
        for (int t = 0; t < 32; ++t) a = fmaf(g[t], W_h2[t*3 + r], a);
        out[(size_t)i*3 + r] = a;
    }
}

// ---------------------------------------------------------------------------
extern "C" void kernel_launch(void* const* d_in, const int* in_sizes, int n_in,
                              void* d_out, int out_size, void* d_ws, size_t ws_size,
                              hipStream_t stream)
{
    const float* seg    = (const float*)d_in[0];
    const float* coord  = (const float*)d_in[1];
    const int*   order  = (const int*)d_in[2];
    const int*   gc     = (const int*)d_in[4];
    const float* W_in   = (const float*)d_in[5];
    const float* b_in   = (const float*)d_in[6];
    const float* g1     = (const float*)d_in[7];
    const float* be1    = (const float*)d_in[8];
    const float* W_qkv  = (const float*)d_in[9];
    const float* b_qkv  = (const float*)d_in[10];
    const float* rpe    = (const float*)d_in[11];
    const float* W_attn = (const float*)d_in[12];
    const float* b_attn = (const float*)d_in[13];
    const float* g2     = (const float*)d_in[14];
    const float* be2    = (const float*)d_in[15];
    const float* W_f1   = (const float*)d_in[16];
    const float* b_f1   = (const float*)d_in[17];
    const float* W_f2   = (const float*)d_in[18];
    const float* b_f2   = (const float*)d_in[19];
    const float* W_h1   = (const float*)d_in[20];
    const float* b_h1   = (const float*)d_in[21];
    const float* W_h2   = (const float*)d_in[22];
    const float* b_h2   = (const float*)d_in[23];

    // workspace layout (fp32): feat[N*64] | qkv[N*192] | attn_out[N*64]
    float* feat = (float*)d_ws;
    float* qkvb = feat + (size_t)N_PTS * 64;
    float* outw = qkvb + (size_t)N_PTS * 192;

    k_in_qkv<<<N_PTS/256, 256, 0, stream>>>(seg, coord, W_in, b_in, g1, be1,
                                            W_qkv, b_qkv, feat, qkvb);
    k_attn<<<NPATCH, 256, 0, stream>>>(qkvb, order, gc, rpe, outw);
    k_ffn<<<N_PTS/256, 256, 0, stream>>>(outw, feat, W_attn, b_attn, g2, be2,
                                         W_f1, b_f1, W_f2, b_f2,
                                         W_h1, b_h1, W_h2, b_h2, (float*)d_out);
}

// Round 10
// 751.171 us; speedup vs baseline: 1.0842x; 1.0842x over previous
//
#include <hip/hip_runtime.h>
#include <hip/hip_fp16.h>
#include <math.h>

// Problem constants (match reference)
#define N_PTS   192000
#define NPATCH  4000      // N/48
#define PK      48        // patch size
#define NH      4         // heads
#define HD      16        // head dim

// Inline erf (Abramowitz & Stegun 7.1.26, |eps| <= 1.5e-7), no libm call.
__device__ __forceinline__ float erf_inl(float x) {
    float ax = fabsf(x);
    float t = 1.0f / fmaf(0.3275911f, ax, 1.0f);
    float poly = fmaf(1.061405429f, t, -1.453152027f);
    poly = fmaf(poly, t, 1.421413741f);
    poly = fmaf(poly, t, -0.284496736f);
    poly = fmaf(poly, t, 0.254829592f);
    poly *= t;
    float e = __expf(-ax * ax);          // native v_exp_f32
    float r = 1.0f - poly * e;
    return copysignf(r, x);
}

__device__ __forceinline__ float gelu_exact(float x) {
    return 0.5f * x * (1.0f + erf_inl(x * 0.70710678118654752f));
}

// ---------------------------------------------------------------------------
// K1: per-point (lane=point): softmax(seg,20)+coord -> feat -> LN1 -> qkv
// EXACT R8-validated version (registers + wave-uniform scalar weight loads).
// R9's LDS-h restructure was neutral for k1 AND perturbed k_ffn's codegen —
// reverted byte-for-byte.
// ---------------------------------------------------------------------------
__global__ __launch_bounds__(256) void k_in_qkv(
    const float* __restrict__ seg, const float* __restrict__ coord,
    const float* __restrict__ W_in, const float* __restrict__ b_in,
    const float* __restrict__ g1, const float* __restrict__ be1,
    const float* __restrict__ W_qkv, const float* __restrict__ b_qkv,
    float* __restrict__ feat_out, float* __restrict__ qkv_out)
{
    int i = blockIdx.x * 256 + threadIdx.x;
    if (i >= N_PTS) return;

    float iv[23];
    {
        const float* s = seg + (size_t)i * 20;
        float mx = -1e30f;
        #pragma unroll
        for (int j = 0; j < 20; ++j) { iv[j] = s[j]; mx = fmaxf(mx, iv[j]); }
        float sum = 0.f;
        #pragma unroll
        for (int j = 0; j < 20; ++j) { iv[j] = __expf(iv[j] - mx); sum += iv[j]; }
        float r = 1.f / sum;
        #pragma unroll
        for (int j = 0; j < 20; ++j) iv[j] *= r;
        iv[20] = coord[(size_t)i*3 + 0];
        iv[21] = coord[(size_t)i*3 + 1];
        iv[22] = coord[(size_t)i*3 + 2];
    }

    // feat = iv @ W_in + b_in   (23x64), W_in row-major [23][64]
    float f[64];
    #pragma unroll
    for (int c = 0; c < 64; ++c) {
        float a = b_in[c];
        #pragma unroll
        for (int j = 0; j < 23; ++j) a = fmaf(iv[j], W_in[j*64 + c], a);
        f[c] = a;
    }
    // store feat (residual use in K3)
    {
        float4* fd = (float4*)(feat_out + (size_t)i * 64);
        #pragma unroll
        for (int c4 = 0; c4 < 16; ++c4)
            fd[c4] = make_float4(f[4*c4], f[4*c4+1], f[4*c4+2], f[4*c4+3]);
    }
    // LN1
    {
        float m = 0.f;
        #pragma unroll
        for (int c = 0; c < 64; ++c) m += f[c];
        m *= (1.f/64.f);
        float v = 0.f;
        #pragma unroll
        for (int c = 0; c < 64; ++c) { float d = f[c]-m; v = fmaf(d, d, v); }
        v *= (1.f/64.f);
        float rs = 1.f / sqrtf(v + 1e-5f);
        #pragma unroll
        for (int c = 0; c < 64; ++c) f[c] = (f[c]-m)*rs*g1[c] + be1[c];
    }
    // qkv = h @ W_qkv + b_qkv   (64x192), W_qkv row-major [64][192]
    {
        float* qd = qkv_out + (size_t)i * 192;
        for (int t4 = 0; t4 < 48; ++t4) {
            const float* bq = b_qkv + t4*4;
            float ax = bq[0], ay = bq[1], az = bq[2], aw = bq[3];
            const float* w = W_qkv + t4*4;
            #pragma unroll
            for (int c = 0; c < 64; ++c) {
                float h = f[c];
                const float* wr = w + c*192;
                ax = fmaf(h, wr[0], ax); ay = fmaf(h, wr[1], ay);
                az = fmaf(h, wr[2], az); aw = fmaf(h, wr[3], aw);
            }
            ((float4*)qd)[t4] = make_float4(ax, ay, az, aw);
        }
    }
}

// ---------------------------------------------------------------------------
// K2: windowed attention. KEPT from R9 (validated correct): rpe_s transposed
// to [h][69] so a wave (uniform h, per-lane idx) reads consecutive words ->
// conflict-free (was banks 4*idx+h -> 3-way, 5.8M SQ_LDS_BANK_CONFLICT in R5).
// ---------------------------------------------------------------------------
__global__ __launch_bounds__(256) void k_attn(
    const float* __restrict__ qkv, const int* __restrict__ order,
    const int* __restrict__ grid_coord, const float* __restrict__ rpe,
    float* __restrict__ outb)
{
    __shared__ float q_s[NH][PK][17];
    __shared__ float k_s[NH][PK][HD];
    __shared__ float v_s[NH][PK][HD];
    __shared__ float rpe_s[276];        // [h][69] transposed layout
    __shared__ int   ord_s[PK];
    __shared__ int   gc_s[PK][3];

    int p = blockIdx.x;
    int tid = threadIdx.x;

    if (tid < PK) ord_s[tid] = order[p*PK + tid];
    for (int t = tid; t < 276; t += 256) {
        int hh2 = t / 69;               // dest head
        int idx = t - hh2 * 69;         // dest rpe index
        rpe_s[t] = rpe[idx*4 + hh2];    // src layout [69][4]
    }
    __syncthreads();

    if (tid < PK) {
        int row = ord_s[tid];
        gc_s[tid][0] = grid_coord[(size_t)row*3 + 0];
        gc_s[tid][1] = grid_coord[(size_t)row*3 + 1];
        gc_s[tid][2] = grid_coord[(size_t)row*3 + 2];
    }
    {
        int lane = tid & 63;
        int hh = lane >> 4, dd = lane & 15;
        for (int rr = tid >> 6; rr < PK; rr += 4) {
            const float* src = qkv + (size_t)ord_s[rr] * 192;
            float qv = src[lane];
            float kv = src[64 + lane];
            float vv = src[128 + lane];
            q_s[hh][rr][dd] = qv;
            k_s[hh][rr][dd] = kv;
            v_s[hh][rr][dd] = vv;
        }
    }
    __syncthreads();

    int h = tid >> 6;
    int r = tid & 63;
    if (r >= PK) return;

    float qr[HD];
    #pragma unroll
    for (int d = 0; d < HD; ++d) qr[d] = q_s[h][r][d];
    int gx = gc_s[r][0], gy = gc_s[r][1], gz = gc_s[r][2];
    int h69 = h * 69;

    float s[PK];
    #pragma unroll 4
    for (int m = 0; m < PK; ++m) {
        float a = 0.f;
        #pragma unroll
        for (int d = 0; d < HD; ++d) a = fmaf(qr[d], k_s[h][m][d], a);
        a *= 0.25f;
        int i0 = min(max(gx - gc_s[m][0], -11), 11) + 11;
        int i1 = min(max(gy - gc_s[m][1], -11), 11) + 34;
        int i2 = min(max(gz - gc_s[m][2], -11), 11) + 57;
        a += rpe_s[h69 + i0] + rpe_s[h69 + i1] + rpe_s[h69 + i2];
        s[m] = a;
    }

    float mx = -1e30f;
    #pragma unroll
    for (int m = 0; m < PK; ++m) mx = fmaxf(mx, s[m]);
    float sum = 0.f;
    #pragma unroll
    for (int m = 0; m < PK; ++m) { s[m] = __expf(s[m] - mx); sum += s[m]; }
    float rinv = 1.f / sum;

    float acc[HD];
    #pragma unroll
    for (int d = 0; d < HD; ++d) acc[d] = 0.f;
    #pragma unroll 4
    for (int m = 0; m < PK; ++m) {
        float pv = s[m] * rinv;
        #pragma unroll
        for (int d = 0; d < HD; ++d) acc[d] = fmaf(pv, v_s[h][m][d], acc[d]);
    }
    {
        float* dst = outb + (size_t)ord_s[r]*64 + h*HD;
        float4* d4 = (float4*)dst;
        #pragma unroll
        for (int d4i = 0; d4i < 4; ++d4i)
            d4[d4i] = make_float4(acc[4*d4i], acc[4*d4i+1], acc[4*d4i+2], acc[4*d4i+3]);
    }
}

// ---------------------------------------------------------------------------
// K3: R8-validated version, byte-identical (305 µs, VALUBusy 64%, no scratch).
// ---------------------------------------------------------------------------
__global__ __launch_bounds__(256) void k_ffn(
    const float* __restrict__ outb, const float* __restrict__ featb,
    const float* __restrict__ W_attn, const float* __restrict__ b_attn,
    const float* __restrict__ g2, const float* __restrict__ be2,
    const float* __restrict__ W_f1, const float* __restrict__ b_f1,
    const float* __restrict__ W_f2, const float* __restrict__ b_f2,
    const float* __restrict__ W_h1, const float* __restrict__ b_h1,
    const float* __restrict__ W_h2, const float* __restrict__ b_h2,
    float* __restrict__ out)
{
    __shared__ __half shh[64][256];   // 32 KB; hh[c] of thread t at [c][t]

    int tid = threadIdx.x;
    int i = blockIdx.x * 256 + tid;
    if (i >= N_PTS) return;

    float o[64];
    {
        const float4* os = (const float4*)(outb + (size_t)i * 64);
        #pragma unroll
        for (int c4 = 0; c4 < 16; ++c4) {
            float4 t = os[c4];
            o[4*c4]=t.x; o[4*c4+1]=t.y; o[4*c4+2]=t.z; o[4*c4+3]=t.w;
        }
    }
    // attn_out = o @ W_attn + b_attn  (64x64)
    float f[64];
    #pragma unroll
    for (int c = 0; c < 64; ++c) {
        float a = b_attn[c];
        #pragma unroll
        for (int k = 0; k < 64; ++k) a = fmaf(o[k], W_attn[k*64 + c], a);
        f[c] = a;
    }
    // + residual feat
    {
        const float4* fs = (const float4*)(featb + (size_t)i * 64);
        #pragma unroll
        for (int c4 = 0; c4 < 16; ++c4) {
            float4 t = fs[c4];
            f[4*c4]+=t.x; f[4*c4+1]+=t.y; f[4*c4+2]+=t.z; f[4*c4+3]+=t.w;
        }
    }
    // LN2 -> hh stored to own LDS column (same-thread RAW only, no barrier)
    {
        float m = 0.f;
        #pragma unroll
        for (int c = 0; c < 64; ++c) m += f[c];
        m *= (1.f/64.f);
        float v = 0.f;
        #pragma unroll
        for (int c = 0; c < 64; ++c) { float d = f[c]-m; v = fmaf(d, d, v); }
        v *= (1.f/64.f);
        float rs = 1.f / sqrtf(v + 1e-5f);
        #pragma unroll
        for (int c = 0; c < 64; ++c)
            shh[c][tid] = __float2half((f[c]-m)*rs*g2[c] + be2[c]);
    }
    // FFN residual: f += gelu(hh@W_f1+b_f1)@W_f2 + b_f2 ; chunked 16 cols
    #pragma unroll
    for (int c = 0; c < 64; ++c) f[c] += b_f2[c];
    for (int t0 = 0; t0 < 16; ++t0) {
        float a[16];
        #pragma unroll
        for (int tt = 0; tt < 16; ++tt) a[tt] = b_f1[t0*16 + tt];
        #pragma unroll
        for (int c = 0; c < 64; ++c) {
            float hv = __half2float(shh[c][tid]);
            const float* w = W_f1 + c*256 + t0*16;
            #pragma unroll
            for (int tt = 0; tt < 16; ++tt) a[tt] = fmaf(hv, w[tt], a[tt]);
        }
        #pragma unroll
        for (int tt = 0; tt < 16; ++tt) a[tt] = gelu_exact(a[tt]);
        #pragma unroll
        for (int tt = 0; tt < 16; ++tt) {
            float av = a[tt];
            const float* w2 = W_f2 + (t0*16 + tt)*64;
            #pragma unroll
            for (int c = 0; c < 64; ++c) f[c] = fmaf(av, w2[c], f[c]);
        }
    }
    // head: gelu(f@W_h1+b_h1) @ W_h2 + b_h2
    float g[32];
    #pragma unroll
    for (int t = 0; t < 32; ++t) {
        float a = b_h1[t];
        #pragma unroll
        for (int c = 0; c < 64; ++c) a = fmaf(f[c], W_h1[c*32 + t], a);
        g[t] = gelu_exact(a);
    }
    #pragma unroll
    for (int r = 0; r < 3; ++r) {
        float a = b_h2[r];
        #pragma unroll
        for (int t = 0; t < 32; ++t) a = fmaf(g[t], W_h2[t*3 + r], a);
        out[(size_t)i*3 + r] = a;
    }
}

// ---------------------------------------------------------------------------
extern "C" void kernel_launch(void* const* d_in, const int* in_sizes, int n_in,
                              void* d_out, int out_size, void* d_ws, size_t ws_size,
                              hipStream_t stream)
{
    const float* seg    = (const float*)d_in[0];
    const float* coord  = (const float*)d_in[1];
    const int*   order  = (const int*)d_in[2];
    const int*   gc     = (const int*)d_in[4];
    const float* W_in   = (const float*)d_in[5];
    const float* b_in   = (const float*)d_in[6];
    const float* g1     = (const float*)d_in[7];
    const float* be1    = (const float*)d_in[8];
    const float* W_qkv  = (const float*)d_in[9];
    const float* b_qkv  = (const float*)d_in[10];
    const float* rpe    = (const float*)d_in[11];
    const float* W_attn = (const float*)d_in[12];
    const float* b_attn = (const float*)d_in[13];
    const float* g2     = (const float*)d_in[14];
    const float* be2    = (const float*)d_in[15];
    const float* W_f1   = (const float*)d_in[16];
    const float* b_f1   = (const float*)d_in[17];
    const float* W_f2   = (const float*)d_in[18];
    const float* b_f2   = (const float*)d_in[19];
    const float* W_h1   = (const float*)d_in[20];
    const float* b_h1   = (const float*)d_in[21];
    const float* W_h2   = (const float*)d_in[22];
    const float* b_h2   = (const float*)d_in[23];

    // workspace layout (fp32): feat[N*64] | qkv[N*192] | attn_out[N*64]
    float* feat = (float*)d_ws;
    float* qkvb = feat + (size_t)N_PTS * 64;
    float* outw = qkvb + (size_t)N_PTS * 192;

    k_in_qkv<<<N_PTS/256, 256, 0, stream>>>(seg, coord, W_in, b_in, g1, be1,
                                            W_qkv, b_qkv, feat, qkvb);
    k_attn<<<NPATCH, 256, 0, stream>>>(qkvb, order, gc, rpe, outw);
    k_ffn<<<N_PTS/256, 256, 0, stream>>>(outw, feat, W_attn, b_attn, g2, be2,
                                         W_f1, b_f1, W_f2, b_f2,
                                         W_h1, b_h1, W_h2, b_h2, (float*)d_out);
}

// Round 11
// 657.008 us; speedup vs baseline: 1.2396x; 1.1433x over previous
//
#include <hip/hip_runtime.h>
#include <hip/hip_fp16.h>
#include <math.h>

// Problem constants (match reference)
#define N_PTS   192000
#define NPATCH  4000      // N/48
#define PK      48        // patch size
#define NH      4         // heads
#define HD      16        // head dim

// Inline erf (Abramowitz & Stegun 7.1.26, |eps| <= 1.5e-7), no libm call.
__device__ __forceinline__ float erf_inl(float x) {
    float ax = fabsf(x);
    float t = 1.0f / fmaf(0.3275911f, ax, 1.0f);
    float poly = fmaf(1.061405429f, t, -1.453152027f);
    poly = fmaf(poly, t, 1.421413741f);
    poly = fmaf(poly, t, -0.284496736f);
    poly = fmaf(poly, t, 0.254829592f);
    poly *= t;
    float e = __expf(-ax * ax);          // native v_exp_f32
    float r = 1.0f - poly * e;
    return copysignf(r, x);
}

__device__ __forceinline__ float gelu_exact(float x) {
    return 0.5f * x * (1.0f + erf_inl(x * 0.70710678118654752f));
}

// ---------------------------------------------------------------------------
// K1: per-point (lane=point): softmax(seg,20)+coord -> feat -> LN1 -> qkv
// EXACT R8/R10-validated version — byte-identical (protects k_ffn codegen).
// ---------------------------------------------------------------------------
__global__ __launch_bounds__(256) void k_in_qkv(
    const float* __restrict__ seg, const float* __restrict__ coord,
    const float* __restrict__ W_in, const float* __restrict__ b_in,
    const float* __restrict__ g1, const float* __restrict__ be1,
    const float* __restrict__ W_qkv, const float* __restrict__ b_qkv,
    float* __restrict__ feat_out, float* __restrict__ qkv_out)
{
    int i = blockIdx.x * 256 + threadIdx.x;
    if (i >= N_PTS) return;

    float iv[23];
    {
        const float* s = seg + (size_t)i * 20;
        float mx = -1e30f;
        #pragma unroll
        for (int j = 0; j < 20; ++j) { iv[j] = s[j]; mx = fmaxf(mx, iv[j]); }
        float sum = 0.f;
        #pragma unroll
        for (int j = 0; j < 20; ++j) { iv[j] = __expf(iv[j] - mx); sum += iv[j]; }
        float r = 1.f / sum;
        #pragma unroll
        for (int j = 0; j < 20; ++j) iv[j] *= r;
        iv[20] = coord[(size_t)i*3 + 0];
        iv[21] = coord[(size_t)i*3 + 1];
        iv[22] = coord[(size_t)i*3 + 2];
    }

    // feat = iv @ W_in + b_in   (23x64), W_in row-major [23][64]
    float f[64];
    #pragma unroll
    for (int c = 0; c < 64; ++c) {
        float a = b_in[c];
        #pragma unroll
        for (int j = 0; j < 23; ++j) a = fmaf(iv[j], W_in[j*64 + c], a);
        f[c] = a;
    }
    // store feat (residual use in K3)
    {
        float4* fd = (float4*)(feat_out + (size_t)i * 64);
        #pragma unroll
        for (int c4 = 0; c4 < 16; ++c4)
            fd[c4] = make_float4(f[4*c4], f[4*c4+1], f[4*c4+2], f[4*c4+3]);
    }
    // LN1
    {
        float m = 0.f;
        #pragma unroll
        for (int c = 0; c < 64; ++c) m += f[c];
        m *= (1.f/64.f);
        float v = 0.f;
        #pragma unroll
        for (int c = 0; c < 64; ++c) { float d = f[c]-m; v = fmaf(d, d, v); }
        v *= (1.f/64.f);
        float rs = 1.f / sqrtf(v + 1e-5f);
        #pragma unroll
        for (int c = 0; c < 64; ++c) f[c] = (f[c]-m)*rs*g1[c] + be1[c];
    }
    // qkv = h @ W_qkv + b_qkv   (64x192), W_qkv row-major [64][192]
    {
        float* qd = qkv_out + (size_t)i * 192;
        for (int t4 = 0; t4 < 48; ++t4) {
            const float* bq = b_qkv + t4*4;
            float ax = bq[0], ay = bq[1], az = bq[2], aw = bq[3];
            const float* w = W_qkv + t4*4;
            #pragma unroll
            for (int c = 0; c < 64; ++c) {
                float h = f[c];
                const float* wr = w + c*192;
                ax = fmaf(h, wr[0], ax); ay = fmaf(h, wr[1], ay);
                az = fmaf(h, wr[2], az); aw = fmaf(h, wr[3], aw);
            }
            ((float4*)qd)[t4] = make_float4(ax, ay, az, aw);
        }
    }
}

// ---------------------------------------------------------------------------
// K2: windowed attention. THIS ROUND: flash-style ONLINE softmax — the s[48]
// score array (spilled to scratch per R5 counters: VGPR=52, WRITE 314MB vs
// 49MB legitimate) is eliminated. Running (m, l, acc[16]) with rescale.
// rpe_s kept transposed [h][69] (conflict-free).
// ---------------------------------------------------------------------------
__global__ __launch_bounds__(256) void k_attn(
    const float* __restrict__ qkv, const int* __restrict__ order,
    const int* __restrict__ grid_coord, const float* __restrict__ rpe,
    float* __restrict__ outb)
{
    __shared__ float q_s[NH][PK][17];
    __shared__ float k_s[NH][PK][HD];
    __shared__ float v_s[NH][PK][HD];
    __shared__ float rpe_s[276];        // [h][69] transposed layout
    __shared__ int   ord_s[PK];
    __shared__ int   gc_s[PK][3];

    int p = blockIdx.x;
    int tid = threadIdx.x;

    if (tid < PK) ord_s[tid] = order[p*PK + tid];
    for (int t = tid; t < 276; t += 256) {
        int hh2 = t / 69;               // dest head
        int idx = t - hh2 * 69;         // dest rpe index
        rpe_s[t] = rpe[idx*4 + hh2];    // src layout [69][4]
    }
    __syncthreads();

    if (tid < PK) {
        int row = ord_s[tid];
        gc_s[tid][0] = grid_coord[(size_t)row*3 + 0];
        gc_s[tid][1] = grid_coord[(size_t)row*3 + 1];
        gc_s[tid][2] = grid_coord[(size_t)row*3 + 2];
    }
    {
        int lane = tid & 63;
        int hh = lane >> 4, dd = lane & 15;
        for (int rr = tid >> 6; rr < PK; rr += 4) {
            const float* src = qkv + (size_t)ord_s[rr] * 192;
            float qv = src[lane];
            float kv = src[64 + lane];
            float vv = src[128 + lane];
            q_s[hh][rr][dd] = qv;
            k_s[hh][rr][dd] = kv;
            v_s[hh][rr][dd] = vv;
        }
    }
    __syncthreads();

    int h = tid >> 6;
    int r = tid & 63;
    if (r >= PK) return;

    float qr[HD];
    #pragma unroll
    for (int d = 0; d < HD; ++d) qr[d] = q_s[h][r][d];
    int gx = gc_s[r][0], gy = gc_s[r][1], gz = gc_s[r][2];
    int h69 = h * 69;

    // online softmax + PV: no score array, no scratch
    float m_run = -1e30f, l_run = 0.f;
    float acc[HD];
    #pragma unroll
    for (int d = 0; d < HD; ++d) acc[d] = 0.f;

    #pragma unroll 4
    for (int m = 0; m < PK; ++m) {
        float a = 0.f;
        #pragma unroll
        for (int d = 0; d < HD; ++d) a = fmaf(qr[d], k_s[h][m][d], a);
        a *= 0.25f;
        int i0 = min(max(gx - gc_s[m][0], -11), 11) + 11;
        int i1 = min(max(gy - gc_s[m][1], -11), 11) + 34;
        int i2 = min(max(gz - gc_s[m][2], -11), 11) + 57;
        a += rpe_s[h69 + i0] + rpe_s[h69 + i1] + rpe_s[h69 + i2];

        float m_new = fmaxf(m_run, a);
        float scale = __expf(m_run - m_new);   // 0 on first iter (exp(-inf))
        float pvv   = __expf(a - m_new);
        l_run = fmaf(l_run, scale, pvv);
        #pragma unroll
        for (int d = 0; d < HD; ++d)
            acc[d] = fmaf(acc[d], scale, pvv * v_s[h][m][d]);
        m_run = m_new;
    }
    float rinv = 1.f / l_run;

    {
        float* dst = outb + (size_t)ord_s[r]*64 + h*HD;
        float4* d4 = (float4*)dst;
        #pragma unroll
        for (int d4i = 0; d4i < 4; ++d4i)
            d4[d4i] = make_float4(acc[4*d4i]*rinv, acc[4*d4i+1]*rinv,
                                  acc[4*d4i+2]*rinv, acc[4*d4i+3]*rinv);
    }
}

// ---------------------------------------------------------------------------
// K3: R8/R10-validated version, byte-identical (308 µs, VALUBusy 65%).
// ---------------------------------------------------------------------------
__global__ __launch_bounds__(256) void k_ffn(
    const float* __restrict__ outb, const float* __restrict__ featb,
    const float* __restrict__ W_attn, const float* __restrict__ b_attn,
    const float* __restrict__ g2, const float* __restrict__ be2,
    const float* __restrict__ W_f1, const float* __restrict__ b_f1,
    const float* __restrict__ W_f2, const float* __restrict__ b_f2,
    const float* __restrict__ W_h1, const float* __restrict__ b_h1,
    const float* __restrict__ W_h2, const float* __restrict__ b_h2,
    float* __restrict__ out)
{
    __shared__ __half shh[64][256];   // 32 KB; hh[c] of thread t at [c][t]

    int tid = threadIdx.x;
    int i = blockIdx.x * 256 + tid;
    if (i >= N_PTS) return;

    float o[64];
    {
        const float4* os = (const float4*)(outb + (size_t)i * 64);
        #pragma unroll
        for (int c4 = 0; c4 < 16; ++c4) {
            float4 t = os[c4];
            o[4*c4]=t.x; o[4*c4+1]=t.y; o[4*c4+2]=t.z; o[4*c4+3]=t.w;
        }
    }
    // attn_out = o @ W_attn + b_attn  (64x64)
    float f[64];
    #pragma unroll
    for (int c = 0; c < 64; ++c) {
        float a = b_attn[c];
        #pragma unroll
        for (int k = 0; k < 64; ++k) a = fmaf(o[k], W_attn[k*64 + c], a);
        f[c] = a;
    }
    // + residual feat
    {
        const float4* fs = (const float4*)(featb + (size_t)i * 64);
        #pragma unroll
        for (int c4 = 0; c4 < 16; ++c4) {
            float4 t = fs[c4];
            f[4*c4]+=t.x; f[4*c4+1]+=t.y; f[4*c4+2]+=t.z; f[4*c4+3]+=t.w;
        }
    }
    // LN2 -> hh stored to own LDS column (same-thread RAW only, no barrier)
    {
        float m = 0.f;
        #pragma unroll
        for (int c = 0; c < 64; ++c) m += f[c];
        m *= (1.f/64.f);
        float v = 0.f;
        #pragma unroll
        for (int c = 0; c < 64; ++c) { float d = f[c]-m; v = fmaf(d, d, v); }
        v *= (1.f/64.f);
        float rs = 1.f / sqrtf(v + 1e-5f);
        #pragma unroll
        for (int c = 0; c < 64; ++c)
            shh[c][tid] = __float2half((f[c]-m)*rs*g2[c] + be2[c]);
    }
    // FFN residual: f += gelu(hh@W_f1+b_f1)@W_f2 + b_f2 ; chunked 16 cols
    #pragma unroll
    for (int c = 0; c < 64; ++c) f[c] += b_f2[c];
    for (int t0 = 0; t0 < 16; ++t0) {
        float a[16];
        #pragma unroll
        for (int tt = 0; tt < 16; ++tt) a[tt] = b_f1[t0*16 + tt];
        #pragma unroll
        for (int c = 0; c < 64; ++c) {
            float hv = __half2float(shh[c][tid]);
            const float* w = W_f1 + c*256 + t0*16;
            #pragma unroll
            for (int tt = 0; tt < 16; ++tt) a[tt] = fmaf(hv, w[tt], a[tt]);
        }
        #pragma unroll
        for (int tt = 0; tt < 16; ++tt) a[tt] = gelu_exact(a[tt]);
        #pragma unroll
        for (int tt = 0; tt < 16; ++tt) {
            float av = a[tt];
            const float* w2 = W_f2 + (t0*16 + tt)*64;
            #pragma unroll
            for (int c = 0; c < 64; ++c) f[c] = fmaf(av, w2[c], f[c]);
        }
    }
    // head: gelu(f@W_h1+b_h1) @ W_h2 + b_h2
    float g[32];
    #pragma unroll
    for (int t = 0; t < 32; ++t) {
        float a = b_h1[t];
        #pragma unroll
        for (int c = 0; c < 64; ++c) a = fmaf(f[c], W_h1[c*32 + t], a);
        g[t] = gelu_exact(a);
    }
    #pragma unroll
    for (int r = 0; r < 3; ++r) {
        float a = b_h2[r];
        #pragma unroll
        for (int t = 0; t < 32; ++t) a = fmaf(g[t], W_h2[t*3 + r], a);
        out[(size_t)i*3 + r] = a;
    }
}

// ---------------------------------------------------------------------------
extern "C" void kernel_launch(void* const* d_in, const int* in_sizes, int n_in,
                              void* d_out, int out_size, void* d_ws, size_t ws_size,
                              hipStream_t stream)
{
    const float* seg    = (const float*)d_in[0];
    const float* coord  = (const float*)d_in[1];
    const int*   order  = (const int*)d_in[2];
    const int*   gc     = (const int*)d_in[4];
    const float* W_in   = (const float*)d_in[5];
    const float* b_in   = (const float*)d_in[6];
    const float* g1     = (const float*)d_in[7];
    const float* be1    = (const float*)d_in[8];
    const float* W_qkv  = (const float*)d_in[9];
    const float* b_qkv  = (const float*)d_in[10];
    const float* rpe    = (const float*)d_in[11];
    const float* W_attn = (const float*)d_in[12];
    const float* b_attn = (const float*)d_in[13];
    const float* g2     = (const float*)d_in[14];
    const float* be2    = (const float*)d_in[15];
    const float* W_f1   = (const float*)d_in[16];
    const float* b_f1   = (const float*)d_in[17];
    const float* W_f2   = (const float*)d_in[18];
    const float* b_f2   = (const float*)d_in[19];
    const float* W_h1   = (const float*)d_in[20];
    const float* b_h1   = (const float*)d_in[21];
    const float* W_h2   = (const float*)d_in[22];
    const float* b_h2   = (const float*)d_in[23];

    // workspace layout (fp32): feat[N*64] | qkv[N*192] | attn_out[N*64]
    float* feat = (float*)d_ws;
    float* qkvb = feat + (size_t)N_PTS * 64;
    float* outw = qkvb + (size_t)N_PTS * 192;

    k_in_qkv<<<N_PTS/256, 256, 0, stream>>>(seg, coord, W_in, b_in, g1, be1,
                                            W_qkv, b_qkv, feat, qkvb);
    k_attn<<<NPATCH, 256, 0, stream>>>(qkvb, order, gc, rpe, outw);
    k_ffn<<<N_PTS/256, 256, 0, stream>>>(outw, feat, W_attn, b_attn, g2, be2,
                                         W_f1, b_f1, W_f2, b_f2,
                                         W_h1, b_h1, W_h2, b_h2, (float*)d_out);
}